// Round 14
// baseline (94.190 us; speedup 1.0000x reference)
//
#include <hip/hip_runtime.h>
#include <math.h>

// Problem constants (match reference setup_inputs)
constexpr int B = 4;
constexpr int S = 64;
constexpr int N = 65536;
constexpr float SLOPE  = 7.0f;
constexpr float LOG2E  = 1.44269504088896340736f;
constexpr float SLOPE2 = SLOPE * LOG2E;   // fold log2(e): sigmoid via exp2 == v_exp_f32

typedef float f32x4 __attribute__((ext_vector_type(4)));

// Tiling
constexpr int THREADS = 256;
constexpr int PTS_PER_THREAD = 4;                        // 4 consecutive points/thread
constexpr int PTS_PER_BLOCK = THREADS * PTS_PER_THREAD;  // 1024
constexpr int S_CHUNK = 16;                              // boxes per block

__global__ __launch_bounds__(THREADS) void box_weight_kernel(
    const float* __restrict__ pos,    // (B,S,3)
    const float* __restrict__ dims,   // (B,S,3)
    const float* __restrict__ rot,    // (B,S,1)
    const float* __restrict__ points, // (B,N,3)
    const int* __restrict__ vmask,    // (B,N) bool staged as int32
    float* __restrict__ out)          // (B,S,N)
{
    const int nchunk = blockIdx.x;
    const int b      = blockIdx.y;
    const int schunk = blockIdx.z;
    const int t      = threadIdx.x;

    // Per-box params: c, s, nbx, nby, ntz, nax, nay, naz
    //   nbx = -(c*tx + s*ty), nby = s*tx - c*ty, ntz = -tz   (rotated, negated offsets)
    //   na* = -SLOPE2 * dim/2                                 (negated log2-domain half-dims)
    __shared__ float bp[S_CHUNK][8];

    if (t < S_CHUNK) {
        const int s_idx = schunk * S_CHUNK + t;
        const int box   = b * S + s_idx;
        const float th  = rot[box];
        const float c   = cosf(th);
        const float sn  = sinf(th);
        const float tx  = pos[box * 3 + 0];
        const float ty  = pos[box * 3 + 1];
        const float tz  = pos[box * 3 + 2];
        bp[t][0] = c;
        bp[t][1] = sn;
        bp[t][2] = -(c * tx + sn * ty);
        bp[t][3] = sn * tx - c * ty;
        bp[t][4] = -tz;
        bp[t][5] = -0.5f * SLOPE2 * dims[box * 3 + 0];
        bp[t][6] = -0.5f * SLOPE2 * dims[box * 3 + 1];
        bp[t][7] = -0.5f * SLOPE2 * dims[box * 3 + 2];
    }
    __syncthreads();

    // ---- load 4 points (12 consecutive floats = 3 aligned float4) ----
    const int n0 = nchunk * PTS_PER_BLOCK + t * PTS_PER_THREAD;
    const float4* p4 =
        reinterpret_cast<const float4*>(points + (size_t)b * N * 3 + (size_t)n0 * 3);
    const float4 A = p4[0];
    const float4 Bv = p4[1];
    const float4 C = p4[2];

    float px[4] = {A.x, A.w, Bv.z, C.y};
    float py[4] = {A.y, Bv.x, Bv.w, C.z};
    float pz[4] = {A.z, Bv.y, C.x, C.w};

    // valid_mask: bool staged as int32. Zero invalid points BEFORE transform (ref semantics).
    const int4 m = *reinterpret_cast<const int4*>(vmask + (size_t)b * N + n0);
    const int mk[4] = {m.x, m.y, m.z, m.w};
#pragma unroll
    for (int k = 0; k < 4; ++k) {
        if (!mk[k]) { px[k] = 0.f; py[k] = 0.f; pz[k] = 0.f; }
    }

    // ---- loop over the 16 boxes of this s-chunk ----
#pragma unroll 1
    for (int i = 0; i < S_CHUNK; ++i) {
        const float c   = bp[i][0];
        const float sn  = bp[i][1];
        const float nbx = bp[i][2];
        const float nby = bp[i][3];
        const float ntz = bp[i][4];
        const float nax = bp[i][5];
        const float nay = bp[i][6];
        const float naz = bp[i][7];

        f32x4 w;
#pragma unroll
        for (int k = 0; k < 4; ++k) {
            // box-frame coords: R^T*(p - t), rotation about z (2 fma each for x,y)
            const float xo = fmaf(c, px[k], fmaf(sn, py[k], nbx));
            const float yo = fmaf(c, py[k], fmaf(-sn, px[k], nby));
            const float zo = pz[k] + ntz;
            // log2-domain logits: e* = 2^(SLOPE2*|coord| - SLOPE2*dim/2)
            const float ex = exp2f(fmaf(SLOPE2, fabsf(xo), nax));
            const float ey = exp2f(fmaf(SLOPE2, fabsf(yo), nay));
            const float ez = exp2f(fmaf(SLOPE2, fabsf(zo), naz));
            // sigmoid product = 1 / ((1+ex)(1+ey)(1+ez)); overflow -> inf -> rcp -> 0 (safe)
            const float denom = (1.f + ex) * (1.f + ey) * (1.f + ez);
            w[k] = __builtin_amdgcn_rcpf(denom);
        }

        const int s_idx = schunk * S_CHUNK + i;
        // Plain coherent store. NOTE: __builtin_nontemporal_store here caused a
        // post-timing stale-data failure (readback saw 0xAA poison remnants after
        // graph replay) — nt no-allocate stores + harness poison fills don't mix.
        f32x4* outp = reinterpret_cast<f32x4*>(
            out + ((size_t)b * S + s_idx) * (size_t)N + n0);
        *outp = w;
    }
}

extern "C" void kernel_launch(void* const* d_in, const int* in_sizes, int n_in,
                              void* d_out, int out_size, void* d_ws, size_t ws_size,
                              hipStream_t stream) {
    const float* pos    = (const float*)d_in[0];
    const float* dims   = (const float*)d_in[1];
    const float* rot    = (const float*)d_in[2];
    const float* points = (const float*)d_in[3];
    const int* vmask    = (const int*)d_in[4];
    float* out = (float*)d_out;

    dim3 grid(N / PTS_PER_BLOCK, B, S / S_CHUNK);  // (64, 4, 4)
    dim3 block(THREADS);
    box_weight_kernel<<<grid, block, 0, stream>>>(pos, dims, rot, points, vmask, out);
}